// Round 1
// baseline (750.976 us; speedup 1.0000x reference)
//
#include <hip/hip_runtime.h>

#define DD 128

// ---------------- CSR build ----------------

__global__ void k_count(const int* __restrict__ ei, int* __restrict__ cnt, int E) {
    int e = blockIdx.x * blockDim.x + threadIdx.x;
    if (e < E) atomicAdd(&cnt[ei[E + e]], 1);
}

__global__ __launch_bounds__(1024) void k_scan(const int* __restrict__ cnt,
                                               int* __restrict__ rowptr,
                                               int* __restrict__ cursor,
                                               int n, int E) {
    __shared__ int part[1024];
    int t = threadIdx.x;
    int chunk = (n + 1023) >> 10;
    int beg = t * chunk;
    int end = min(beg + chunk, n);
    int s = 0;
    for (int i = beg; i < end; ++i) s += cnt[i];
    part[t] = s;
    __syncthreads();
    // Hillis-Steele inclusive scan over 1024 partials
    for (int off = 1; off < 1024; off <<= 1) {
        int v = (t >= off) ? part[t - off] : 0;
        __syncthreads();
        part[t] += v;
        __syncthreads();
    }
    int run = (t == 0) ? 0 : part[t - 1];
    for (int i = beg; i < end; ++i) {
        rowptr[i] = run;
        cursor[i] = run;
        run += cnt[i];
    }
    if (t == 0) rowptr[n] = E;
}

__global__ void k_fill(const int* __restrict__ ei, int* __restrict__ cursor,
                       int* __restrict__ eidx, int E) {
    int e = blockIdx.x * blockDim.x + threadIdx.x;
    if (e < E) {
        int p = atomicAdd(&cursor[ei[E + e]], 1);
        eidx[p] = ei[e];  // src node of edge e
    }
}

// ---------------- mean aggregation: one 64-lane wave per node ----------------

__global__ __launch_bounds__(256) void k_agg(const float* __restrict__ hin,
                                             const int* __restrict__ rowptr,
                                             const int* __restrict__ eidx,
                                             float* __restrict__ agg, int n) {
    int w = (int)((blockIdx.x * (unsigned)blockDim.x + threadIdx.x) >> 6);
    int lane = threadIdx.x & 63;
    if (w >= n) return;
    int beg = rowptr[w], end = rowptr[w + 1];
    int c = lane * 2;
    float ax = 0.f, ay = 0.f;
    for (int e = beg; e < end; ++e) {
        const float2 v = *reinterpret_cast<const float2*>(hin + (size_t)eidx[e] * DD + c);
        ax += v.x;
        ay += v.y;
    }
    float inv = 1.0f / fmaxf((float)(end - beg), 1.0f);
    float2 o;
    o.x = ax * inv;
    o.y = ay * inv;
    *reinterpret_cast<float2*>(agg + (size_t)w * DD + c) = o;
}

// ---------------- out = A @ Wl + H @ Wr + b  (optional relu) ----------------
// Block: 256 threads, 16 nodes. Thread t: row r=t>>4, cols [ (t&15)*8 .. +8 ).
// A/H rows staged in LDS (stride 132 -> distinct banks for the 4 r-values per
// wave). W read as float4 (L2-resident, 128 KB total).

__global__ __launch_bounds__(256) void k_gemm(const float* __restrict__ A,
                                              const float* __restrict__ H,
                                              const float* __restrict__ Wl,
                                              const float* __restrict__ Wr,
                                              const float* __restrict__ bias,
                                              float* __restrict__ out,
                                              int n, int relu) {
    __shared__ float sA[16][132];
    __shared__ float sH[16][132];
    int t = threadIdx.x;
    int node0 = blockIdx.x * 16;
    for (int i = t; i < 512; i += 256) {   // 16 rows * 32 float4
        int r = i >> 5, c4 = i & 31;
        int node = node0 + r;
        float4 va = make_float4(0.f, 0.f, 0.f, 0.f), vh = va;
        if (node < n) {
            va = reinterpret_cast<const float4*>(A + (size_t)node * DD)[c4];
            vh = reinterpret_cast<const float4*>(H + (size_t)node * DD)[c4];
        }
        reinterpret_cast<float4*>(&sA[r][0])[c4] = va;
        reinterpret_cast<float4*>(&sH[r][0])[c4] = vh;
    }
    __syncthreads();

    int r = t >> 4;
    int cg = t & 15;
    const float4* Wl4 = reinterpret_cast<const float4*>(Wl);
    const float4* Wr4 = reinterpret_cast<const float4*>(Wr);
    float acc[8];
#pragma unroll
    for (int i = 0; i < 8; ++i) acc[i] = 0.f;

#pragma unroll 4
    for (int k = 0; k < 128; ++k) {
        float a = sA[r][k];
        float h = sH[r][k];
        float4 wl0 = Wl4[k * 32 + cg * 2];
        float4 wl1 = Wl4[k * 32 + cg * 2 + 1];
        float4 wr0 = Wr4[k * 32 + cg * 2];
        float4 wr1 = Wr4[k * 32 + cg * 2 + 1];
        acc[0] += a * wl0.x + h * wr0.x;
        acc[1] += a * wl0.y + h * wr0.y;
        acc[2] += a * wl0.z + h * wr0.z;
        acc[3] += a * wl0.w + h * wr0.w;
        acc[4] += a * wl1.x + h * wr1.x;
        acc[5] += a * wl1.y + h * wr1.y;
        acc[6] += a * wl1.z + h * wr1.z;
        acc[7] += a * wl1.w + h * wr1.w;
    }

    int node = node0 + r;
    if (node < n) {
        float4 b0 = reinterpret_cast<const float4*>(bias)[cg * 2];
        float4 b1 = reinterpret_cast<const float4*>(bias)[cg * 2 + 1];
        float4 o0, o1;
        o0.x = acc[0] + b0.x; o0.y = acc[1] + b0.y;
        o0.z = acc[2] + b0.z; o0.w = acc[3] + b0.w;
        o1.x = acc[4] + b1.x; o1.y = acc[5] + b1.y;
        o1.z = acc[6] + b1.z; o1.w = acc[7] + b1.w;
        if (relu) {
            o0.x = fmaxf(o0.x, 0.f); o0.y = fmaxf(o0.y, 0.f);
            o0.z = fmaxf(o0.z, 0.f); o0.w = fmaxf(o0.w, 0.f);
            o1.x = fmaxf(o1.x, 0.f); o1.y = fmaxf(o1.y, 0.f);
            o1.z = fmaxf(o1.z, 0.f); o1.w = fmaxf(o1.w, 0.f);
        }
        float* op = out + (size_t)node * DD + cg * 8;
        reinterpret_cast<float4*>(op)[0] = o0;
        reinterpret_cast<float4*>(op)[1] = o1;
    }
}

// ---------------- launch ----------------

extern "C" void kernel_launch(void* const* d_in, const int* in_sizes, int n_in,
                              void* d_out, int out_size, void* d_ws, size_t ws_size,
                              hipStream_t stream) {
    const float* x   = (const float*)d_in[0];
    const int*   ei  = (const int*)d_in[1];
    const float* Wl1 = (const float*)d_in[2];
    const float* Wr1 = (const float*)d_in[3];
    const float* b1  = (const float*)d_in[4];
    const float* Wl2 = (const float*)d_in[5];
    const float* Wr2 = (const float*)d_in[6];
    const float* b2  = (const float*)d_in[7];
    float* out = (float*)d_out;

    int n = in_sizes[0] / DD;
    int E = in_sizes[1] / 2;

    char* ws = (char*)d_ws;
    size_t off = 0;
    auto take = [&](size_t bytes) -> void* {
        void* p = ws + off;
        off = (off + bytes + 255) & ~(size_t)255;
        return p;
    };
    int* cnt     = (int*)take((size_t)n * 4);
    int* rowptr  = (int*)take(((size_t)n + 1) * 4);
    int* cursor  = (int*)take((size_t)n * 4);
    int* eidx    = (int*)take((size_t)E * 4);
    float* agg   = (float*)take((size_t)n * DD * 4);
    float* hbuf  = (float*)take((size_t)n * DD * 4);

    hipMemsetAsync(cnt, 0, (size_t)n * 4, stream);
    k_count<<<(E + 255) / 256, 256, 0, stream>>>(ei, cnt, E);
    k_scan<<<1, 1024, 0, stream>>>(cnt, rowptr, cursor, n, E);
    k_fill<<<(E + 255) / 256, 256, 0, stream>>>(ei, cursor, eidx, E);

    int aggBlocks = (n + 3) / 4;  // 4 waves (nodes) per 256-thread block

    // Layer 1
    k_agg<<<aggBlocks, 256, 0, stream>>>(x, rowptr, eidx, agg, n);
    k_gemm<<<(n + 15) / 16, 256, 0, stream>>>(agg, x, Wl1, Wr1, b1, hbuf, n, 1);
    // Layer 2
    k_agg<<<aggBlocks, 256, 0, stream>>>(hbuf, rowptr, eidx, agg, n);
    k_gemm<<<(n + 15) / 16, 256, 0, stream>>>(agg, hbuf, Wl2, Wr2, b2, out, n, 0);
}

// Round 3
// 360.873 us; speedup vs baseline: 2.0810x; 2.0810x over previous
//
#include <hip/hip_runtime.h>
#include <hip/hip_bf16.h>

#define DD 128

typedef __attribute__((ext_vector_type(8))) short short8v;
typedef __attribute__((ext_vector_type(4))) float f32x4;

static __device__ __forceinline__ ushort f2bf(float f) {
    __hip_bfloat16 b = __float2bfloat16(f);
    return *reinterpret_cast<ushort*>(&b);
}

// ---------------- CSR build ----------------

__global__ void k_count(const int* __restrict__ ei, int* __restrict__ cnt, int E) {
    int e = blockIdx.x * blockDim.x + threadIdx.x;
    if (e < E) atomicAdd(&cnt[ei[E + e]], 1);
}

__global__ __launch_bounds__(1024) void k_scan(const int* __restrict__ cnt,
                                               int* __restrict__ rowptr,
                                               int* __restrict__ cursor,
                                               int n, int E) {
    __shared__ int part[1024];
    int t = threadIdx.x;
    int chunk = (n + 1023) >> 10;
    int beg = t * chunk;
    int end = min(beg + chunk, n);
    int s = 0;
    for (int i = beg; i < end; ++i) s += cnt[i];
    part[t] = s;
    __syncthreads();
    for (int off = 1; off < 1024; off <<= 1) {
        int v = (t >= off) ? part[t - off] : 0;
        __syncthreads();
        part[t] += v;
        __syncthreads();
    }
    int run = (t == 0) ? 0 : part[t - 1];
    for (int i = beg; i < end; ++i) {
        rowptr[i] = run;
        cursor[i] = run;
        run += cnt[i];
    }
    if (t == 0) rowptr[n] = E;
}

__global__ void k_fill(const int* __restrict__ ei, int* __restrict__ cursor,
                       int* __restrict__ eidx, int E) {
    int e = blockIdx.x * blockDim.x + threadIdx.x;
    if (e < E) {
        int p = atomicAdd(&cursor[ei[E + e]], 1);
        eidx[p] = ei[e];  // src node of edge e
    }
}

// ---------------- fp32 -> bf16 cast ----------------

__global__ __launch_bounds__(256) void k_cast(const float* __restrict__ x,
                                              ushort* __restrict__ xbf, int n4) {
    int i = blockIdx.x * blockDim.x + threadIdx.x;
    if (i >= n4) return;
    float4 v = reinterpret_cast<const float4*>(x)[i];
    ushort4 o;
    o.x = f2bf(v.x); o.y = f2bf(v.y); o.z = f2bf(v.z); o.w = f2bf(v.w);
    reinterpret_cast<ushort4*>(xbf)[i] = o;
}

// ---------------- weight prep: Wt[n][k] = bf16( k<128 ? Wl[k][n] : Wr[k-128][n] ) ----

__global__ __launch_bounds__(256) void k_prepw(const float* __restrict__ Wl,
                                               const float* __restrict__ Wr,
                                               ushort* __restrict__ Wt) {
    int idx = blockIdx.x * 256 + threadIdx.x;   // 128*256 = 32768
    int nn = idx >> 8, k = idx & 255;
    float v = (k < 128) ? Wl[k * 128 + nn] : Wr[(k - 128) * 128 + nn];
    Wt[nn * 256 + k] = f2bf(v);
}

// ---------------- mean aggregation (bf16 in/out, fp32 acc): wave per node ----

__global__ __launch_bounds__(256) void k_aggb(const ushort* __restrict__ hin,
                                              const int* __restrict__ rowptr,
                                              const int* __restrict__ eidx,
                                              ushort* __restrict__ aggout, int n) {
    int w = (int)((blockIdx.x * (unsigned)blockDim.x + threadIdx.x) >> 6);
    int lane = threadIdx.x & 63;
    if (w >= n) return;
    int beg = rowptr[w], end = rowptr[w + 1];
    const uint* base = reinterpret_cast<const uint*>(hin);  // 2 bf16 / uint, 64 uints/row
    float ax = 0.f, ay = 0.f;
    int e = beg;
    for (; e + 4 <= end; e += 4) {
        int i0 = eidx[e], i1 = eidx[e + 1], i2 = eidx[e + 2], i3 = eidx[e + 3];
        uint v0 = base[(size_t)i0 * 64 + lane];
        uint v1 = base[(size_t)i1 * 64 + lane];
        uint v2 = base[(size_t)i2 * 64 + lane];
        uint v3 = base[(size_t)i3 * 64 + lane];
        ax += __uint_as_float(v0 << 16);
        ay += __uint_as_float(v0 & 0xffff0000u);
        ax += __uint_as_float(v1 << 16);
        ay += __uint_as_float(v1 & 0xffff0000u);
        ax += __uint_as_float(v2 << 16);
        ay += __uint_as_float(v2 & 0xffff0000u);
        ax += __uint_as_float(v3 << 16);
        ay += __uint_as_float(v3 & 0xffff0000u);
    }
    for (; e < end; ++e) {
        uint v = base[(size_t)eidx[e] * 64 + lane];
        ax += __uint_as_float(v << 16);
        ay += __uint_as_float(v & 0xffff0000u);
    }
    float inv = 1.0f / fmaxf((float)(end - beg), 1.0f);
    uint o = ((uint)f2bf(ay * inv) << 16) | (uint)f2bf(ax * inv);
    reinterpret_cast<uint*>(aggout)[(size_t)w * 64 + lane] = o;
}

// ---------------- MFMA GEMM: out[m][:] = concat(Alow,Ahigh)[m][:] @ Wt^T + b ----
// wave: 16 rows x 128 cols, K=256 (low half from Alow, high half from Ahigh).
// A frag (lane l): A[m0+(l&15)][k0+8*(l>>4)+j]  (contiguous 16B)
// B frag (lane l): Wt[n0+(l&15)][k0+8*(l>>4)+j] (contiguous 16B; Wt = W^T)
// C     (lane l,reg r): C[m0+(l>>4)*4+r][n0+(l&15)]

__global__ __launch_bounds__(256) void k_mm(const ushort* __restrict__ Alow,
                                            const ushort* __restrict__ Ahigh,
                                            const ushort* __restrict__ Wt,
                                            const float* __restrict__ bias,
                                            void* __restrict__ outp,
                                            int n, int relu, int outBf16) {
    int t = threadIdx.x;
    int wv = t >> 6;
    int l = t & 63;
    int lr = l & 15;
    int lk = l >> 4;
    int m0 = blockIdx.x * 64 + wv * 16;
    int arow = m0 + lr;
    if (arow >= n) arow = n - 1;  // clamp; stores are guarded

    f32x4 acc[8];
#pragma unroll
    for (int i = 0; i < 8; ++i) acc[i] = (f32x4){0.f, 0.f, 0.f, 0.f};

    const ushort* arow_lo = Alow + (size_t)arow * DD;
    const ushort* arow_hi = Ahigh + (size_t)arow * DD;

#pragma unroll
    for (int ks = 0; ks < 8; ++ks) {
        int k0 = ks * 32 + lk * 8;
        const ushort* asrc = (k0 < 128) ? (arow_lo + k0) : (arow_hi + (k0 - 128));
        short8v af = *reinterpret_cast<const short8v*>(asrc);
#pragma unroll
        for (int nt = 0; nt < 8; ++nt) {
            short8v bf = *reinterpret_cast<const short8v*>(Wt + (size_t)(nt * 16 + lr) * 256 + k0);
            acc[nt] = __builtin_amdgcn_mfma_f32_16x16x32_bf16(af, bf, acc[nt], 0, 0, 0);
        }
    }

    int crow0 = m0 + lk * 4;
#pragma unroll
    for (int nt = 0; nt < 8; ++nt) {
        int col = nt * 16 + lr;
        float bv = bias[col];
#pragma unroll
        for (int r = 0; r < 4; ++r) {
            int row = crow0 + r;
            if (row < n) {
                float v = acc[nt][r] + bv;
                if (relu) v = fmaxf(v, 0.f);
                if (outBf16) {
                    reinterpret_cast<ushort*>(outp)[(size_t)row * DD + col] = f2bf(v);
                } else {
                    reinterpret_cast<float*>(outp)[(size_t)row * DD + col] = v;
                }
            }
        }
    }
}

// ---------------- launch ----------------

extern "C" void kernel_launch(void* const* d_in, const int* in_sizes, int n_in,
                              void* d_out, int out_size, void* d_ws, size_t ws_size,
                              hipStream_t stream) {
    const float* x   = (const float*)d_in[0];
    const int*   ei  = (const int*)d_in[1];
    const float* Wl1 = (const float*)d_in[2];
    const float* Wr1 = (const float*)d_in[3];
    const float* b1  = (const float*)d_in[4];
    const float* Wl2 = (const float*)d_in[5];
    const float* Wr2 = (const float*)d_in[6];
    const float* b2  = (const float*)d_in[7];
    float* out = (float*)d_out;

    int n = in_sizes[0] / DD;
    int E = in_sizes[1] / 2;

    char* ws = (char*)d_ws;
    size_t off = 0;
    auto take = [&](size_t bytes) -> void* {
        void* p = ws + off;
        off = (off + bytes + 255) & ~(size_t)255;
        return p;
    };
    int* cnt       = (int*)take((size_t)n * 4);
    int* rowptr    = (int*)take(((size_t)n + 1) * 4);
    int* cursor    = (int*)take((size_t)n * 4);
    int* eidx      = (int*)take((size_t)E * 4);
    ushort* xbf    = (ushort*)take((size_t)n * DD * 2);
    ushort* hbf    = (ushort*)take((size_t)n * DD * 2);
    ushort* aggbf  = (ushort*)take((size_t)n * DD * 2);
    ushort* Wt1    = (ushort*)take((size_t)DD * 256 * 2);
    ushort* Wt2    = (ushort*)take((size_t)DD * 256 * 2);

    hipMemsetAsync(cnt, 0, (size_t)n * 4, stream);
    k_count<<<(E + 255) / 256, 256, 0, stream>>>(ei, cnt, E);
    k_scan<<<1, 1024, 0, stream>>>(cnt, rowptr, cursor, n, E);
    k_fill<<<(E + 255) / 256, 256, 0, stream>>>(ei, cursor, eidx, E);

    int n4 = n * DD / 4;
    k_cast<<<(n4 + 255) / 256, 256, 0, stream>>>(x, xbf, n4);
    k_prepw<<<128, 256, 0, stream>>>(Wl1, Wr1, Wt1);
    k_prepw<<<128, 256, 0, stream>>>(Wl2, Wr2, Wt2);

    int aggBlocks = (n + 3) / 4;       // 4 waves (nodes) / block
    int mmBlocks  = (n + 63) / 64;     // 64 rows / block

    // Layer 1: h = relu(mean_agg(xbf) @ Wl1 + b1 + xbf @ Wr1)
    k_aggb<<<aggBlocks, 256, 0, stream>>>(xbf, rowptr, eidx, aggbf, n);
    k_mm<<<mmBlocks, 256, 0, stream>>>(aggbf, xbf, Wt1, b1, hbf, n, 1, 1);
    // Layer 2: out = mean_agg(hbf) @ Wl2 + b2 + hbf @ Wr2
    k_aggb<<<aggBlocks, 256, 0, stream>>>(hbf, rowptr, eidx, aggbf, n);
    k_mm<<<mmBlocks, 256, 0, stream>>>(aggbf, hbf, Wt2, b2, out, n, 0, 0);
}

// Round 4
// 261.529 us; speedup vs baseline: 2.8715x; 1.3799x over previous
//
#include <hip/hip_runtime.h>
#include <hip/hip_bf16.h>

#define DD 128

typedef __attribute__((ext_vector_type(8))) short short8v;
typedef __attribute__((ext_vector_type(4))) float f32x4;

static __device__ __forceinline__ ushort f2bf(float f) {
    __hip_bfloat16 b = __float2bfloat16(f);
    return *reinterpret_cast<ushort*>(&b);
}

// ---------------- CSR build ----------------

__global__ void k_count(const int* __restrict__ ei, int* __restrict__ cnt, int E) {
    int e = blockIdx.x * blockDim.x + threadIdx.x;
    if (e < E) atomicAdd(&cnt[ei[E + e]], 1);
}

// two-level scan: one node per thread
__global__ __launch_bounds__(256) void k_scan1(const int* __restrict__ cnt,
                                               int* __restrict__ incl,
                                               int* __restrict__ bsum, int n) {
    __shared__ int s[256];
    int t = threadIdx.x;
    int i = blockIdx.x * 256 + t;
    int v = (i < n) ? cnt[i] : 0;
    s[t] = v;
    __syncthreads();
#pragma unroll
    for (int off = 1; off < 256; off <<= 1) {
        int u = (t >= off) ? s[t - off] : 0;
        __syncthreads();
        s[t] += u;
        __syncthreads();
    }
    if (i < n) incl[i] = s[t];
    if (t == 255) bsum[blockIdx.x] = s[255];
}

__global__ __launch_bounds__(256) void k_scan2(int* __restrict__ bsum, int nb) {
    __shared__ int s[256];
    int t = threadIdx.x;
    s[t] = (t < nb) ? bsum[t] : 0;
    __syncthreads();
#pragma unroll
    for (int off = 1; off < 256; off <<= 1) {
        int u = (t >= off) ? s[t - off] : 0;
        __syncthreads();
        s[t] += u;
        __syncthreads();
    }
    // exclusive
    if (t < nb) bsum[t] = (t == 0) ? 0 : s[t - 1];
}

__global__ __launch_bounds__(256) void k_scan3(const int* __restrict__ cnt,
                                               const int* __restrict__ incl,
                                               const int* __restrict__ bsum,
                                               int* __restrict__ rowptr,
                                               int* __restrict__ cursor,
                                               int n, int E) {
    int i = blockIdx.x * 256 + threadIdx.x;
    if (i < n) {
        int r = bsum[blockIdx.x] + incl[i] - cnt[i];
        rowptr[i] = r;
        cursor[i] = r;
    }
    if (i == 0) rowptr[n] = E;
}

__global__ void k_fill(const int* __restrict__ ei, int* __restrict__ cursor,
                       int* __restrict__ eidx, int E) {
    int e = blockIdx.x * blockDim.x + threadIdx.x;
    if (e < E) {
        int p = atomicAdd(&cursor[ei[E + e]], 1);
        eidx[p] = ei[e];  // src node of edge e
    }
}

// ---------------- fp32 -> bf16 cast ----------------

__global__ __launch_bounds__(256) void k_cast(const float* __restrict__ x,
                                              ushort* __restrict__ xbf, int n4) {
    int i = blockIdx.x * blockDim.x + threadIdx.x;
    if (i >= n4) return;
    float4 v = reinterpret_cast<const float4*>(x)[i];
    ushort4 o;
    o.x = f2bf(v.x); o.y = f2bf(v.y); o.z = f2bf(v.z); o.w = f2bf(v.w);
    reinterpret_cast<ushort4*>(xbf)[i] = o;
}

// ---------------- weight prep: Wt[n][k] = bf16( k<128 ? Wl[k][n] : Wr[k-128][n] ) ----

__global__ __launch_bounds__(256) void k_prepw(const float* __restrict__ Wl,
                                               const float* __restrict__ Wr,
                                               ushort* __restrict__ Wt) {
    int idx = blockIdx.x * 256 + threadIdx.x;   // 128*256 = 32768
    int nn = idx >> 8, k = idx & 255;
    float v = (k < 128) ? Wl[k * 128 + nn] : Wr[(k - 128) * 128 + nn];
    Wt[nn * 256 + k] = f2bf(v);
}

// ---------------- mean aggregation (bf16 in/out, fp32 acc): wave per node ----

__global__ __launch_bounds__(256) void k_aggb(const ushort* __restrict__ hin,
                                              const int* __restrict__ rowptr,
                                              const int* __restrict__ eidx,
                                              ushort* __restrict__ aggout, int n) {
    int w = (int)((blockIdx.x * (unsigned)blockDim.x + threadIdx.x) >> 6);
    int lane = threadIdx.x & 63;
    if (w >= n) return;
    int beg = rowptr[w], end = rowptr[w + 1];
    const uint* base = reinterpret_cast<const uint*>(hin);  // 2 bf16 / uint, 64 uints/row
    float ax = 0.f, ay = 0.f;
    int e = beg;
    for (; e + 4 <= end; e += 4) {
        int i0 = eidx[e], i1 = eidx[e + 1], i2 = eidx[e + 2], i3 = eidx[e + 3];
        uint v0 = base[(size_t)i0 * 64 + lane];
        uint v1 = base[(size_t)i1 * 64 + lane];
        uint v2 = base[(size_t)i2 * 64 + lane];
        uint v3 = base[(size_t)i3 * 64 + lane];
        ax += __uint_as_float(v0 << 16);
        ay += __uint_as_float(v0 & 0xffff0000u);
        ax += __uint_as_float(v1 << 16);
        ay += __uint_as_float(v1 & 0xffff0000u);
        ax += __uint_as_float(v2 << 16);
        ay += __uint_as_float(v2 & 0xffff0000u);
        ax += __uint_as_float(v3 << 16);
        ay += __uint_as_float(v3 & 0xffff0000u);
    }
    for (; e < end; ++e) {
        uint v = base[(size_t)eidx[e] * 64 + lane];
        ax += __uint_as_float(v << 16);
        ay += __uint_as_float(v & 0xffff0000u);
    }
    float inv = 1.0f / fmaxf((float)(end - beg), 1.0f);
    uint o = ((uint)f2bf(ay * inv) << 16) | (uint)f2bf(ax * inv);
    reinterpret_cast<uint*>(aggout)[(size_t)w * 64 + lane] = o;
}

// ---------------- MFMA GEMM: out[m][:] = concat(Alow,Ahigh)[m][:] @ Wt^T + b ----
// wave: 16 rows x 128 cols, K=256 (low half from Alow, high half from Ahigh).
// A frag (lane l): A[m0+(l&15)][k0+8*(l>>4)+j]  (contiguous 16B)
// B frag (lane l): Wt[n0+(l&15)][k0+8*(l>>4)+j] (contiguous 16B; Wt = W^T)
// C     (lane l,reg r): C[m0+(l>>4)*4+r][n0+(l&15)]

__global__ __launch_bounds__(256) void k_mm(const ushort* __restrict__ Alow,
                                            const ushort* __restrict__ Ahigh,
                                            const ushort* __restrict__ Wt,
                                            const float* __restrict__ bias,
                                            void* __restrict__ outp,
                                            int n, int relu, int outBf16) {
    int t = threadIdx.x;
    int wv = t >> 6;
    int l = t & 63;
    int lr = l & 15;
    int lk = l >> 4;
    int m0 = blockIdx.x * 64 + wv * 16;
    int arow = m0 + lr;
    if (arow >= n) arow = n - 1;  // clamp; stores are guarded

    f32x4 acc[8];
#pragma unroll
    for (int i = 0; i < 8; ++i) acc[i] = (f32x4){0.f, 0.f, 0.f, 0.f};

    const ushort* arow_lo = Alow + (size_t)arow * DD;
    const ushort* arow_hi = Ahigh + (size_t)arow * DD;

#pragma unroll
    for (int ks = 0; ks < 8; ++ks) {
        int k0 = ks * 32 + lk * 8;
        const ushort* asrc = (k0 < 128) ? (arow_lo + k0) : (arow_hi + (k0 - 128));
        short8v af = *reinterpret_cast<const short8v*>(asrc);
#pragma unroll
        for (int nt = 0; nt < 8; ++nt) {
            short8v bf = *reinterpret_cast<const short8v*>(Wt + (size_t)(nt * 16 + lr) * 256 + k0);
            acc[nt] = __builtin_amdgcn_mfma_f32_16x16x32_bf16(af, bf, acc[nt], 0, 0, 0);
        }
    }

    int crow0 = m0 + lk * 4;
#pragma unroll
    for (int nt = 0; nt < 8; ++nt) {
        int col = nt * 16 + lr;
        float bv = bias[col];
#pragma unroll
        for (int r = 0; r < 4; ++r) {
            int row = crow0 + r;
            if (row < n) {
                float v = acc[nt][r] + bv;
                if (relu) v = fmaxf(v, 0.f);
                if (outBf16) {
                    reinterpret_cast<ushort*>(outp)[(size_t)row * DD + col] = f2bf(v);
                } else {
                    reinterpret_cast<float*>(outp)[(size_t)row * DD + col] = v;
                }
            }
        }
    }
}

// ---------------- launch ----------------

extern "C" void kernel_launch(void* const* d_in, const int* in_sizes, int n_in,
                              void* d_out, int out_size, void* d_ws, size_t ws_size,
                              hipStream_t stream) {
    const float* x   = (const float*)d_in[0];
    const int*   ei  = (const int*)d_in[1];
    const float* Wl1 = (const float*)d_in[2];
    const float* Wr1 = (const float*)d_in[3];
    const float* b1  = (const float*)d_in[4];
    const float* Wl2 = (const float*)d_in[5];
    const float* Wr2 = (const float*)d_in[6];
    const float* b2  = (const float*)d_in[7];
    float* out = (float*)d_out;

    int n = in_sizes[0] / DD;
    int E = in_sizes[1] / 2;

    char* ws = (char*)d_ws;
    size_t off = 0;
    auto take = [&](size_t bytes) -> void* {
        void* p = ws + off;
        off = (off + bytes + 255) & ~(size_t)255;
        return p;
    };
    int* cnt       = (int*)take((size_t)n * 4);
    int* rowptr    = (int*)take(((size_t)n + 1) * 4);
    int* cursor    = (int*)take((size_t)n * 4);
    int* incl      = (int*)take((size_t)n * 4);
    int* bsum      = (int*)take(1024);
    int* eidx      = (int*)take((size_t)E * 4);
    ushort* xbf    = (ushort*)take((size_t)n * DD * 2);
    ushort* hbf    = (ushort*)take((size_t)n * DD * 2);
    ushort* aggbf  = (ushort*)take((size_t)n * DD * 2);
    ushort* Wt1    = (ushort*)take((size_t)DD * 256 * 2);
    ushort* Wt2    = (ushort*)take((size_t)DD * 256 * 2);

    int scanBlocks = (n + 255) / 256;   // 196 <= 256

    hipMemsetAsync(cnt, 0, (size_t)n * 4, stream);
    k_count<<<(E + 255) / 256, 256, 0, stream>>>(ei, cnt, E);
    k_scan1<<<scanBlocks, 256, 0, stream>>>(cnt, incl, bsum, n);
    k_scan2<<<1, 256, 0, stream>>>(bsum, scanBlocks);
    k_scan3<<<scanBlocks, 256, 0, stream>>>(cnt, incl, bsum, rowptr, cursor, n, E);
    k_fill<<<(E + 255) / 256, 256, 0, stream>>>(ei, cursor, eidx, E);

    int n4 = n * DD / 4;
    k_cast<<<(n4 + 255) / 256, 256, 0, stream>>>(x, xbf, n4);
    k_prepw<<<128, 256, 0, stream>>>(Wl1, Wr1, Wt1);
    k_prepw<<<128, 256, 0, stream>>>(Wl2, Wr2, Wt2);

    int aggBlocks = (n + 3) / 4;       // 4 waves (nodes) / block
    int mmBlocks  = (n + 63) / 64;     // 64 rows / block

    // Layer 1: h = relu(mean_agg(xbf) @ Wl1 + b1 + xbf @ Wr1)
    k_aggb<<<aggBlocks, 256, 0, stream>>>(xbf, rowptr, eidx, aggbf, n);
    k_mm<<<mmBlocks, 256, 0, stream>>>(aggbf, xbf, Wt1, b1, hbf, n, 1, 1);
    // Layer 2: out = mean_agg(hbf) @ Wl2 + b2 + hbf @ Wr2
    k_aggb<<<aggBlocks, 256, 0, stream>>>(hbf, rowptr, eidx, aggbf, n);
    k_mm<<<mmBlocks, 256, 0, stream>>>(aggbf, hbf, Wt2, b2, out, n, 0, 0);
}